// Round 8
// baseline (418.838 us; speedup 1.0000x reference)
//
#include <hip/hip_runtime.h>
#include <math.h>

#define Bn 8
#define Cn 64
#define Hn 96
#define Wn 96
#define HWn (Hn*Wn)
#define OCn 64
#define Kn 9
#define OFFCn 27
#define NPIX (Bn*HWn)        // 73728 = 1152*64
#define PGRPS (NPIX/64)      // 1152 pixel groups

// ws layout: float pwbuf[4][9][NPIX]; int abuf[9][NPIX]; short wpack[40960]
#define WS_PARAM_DWORDS (45*NPIX)
#define WPACK_SHORTS (4*20*64*8)                    // 40960 bf16 = 80 KB
#define WS_BYTES ((size_t)WS_PARAM_DWORDS*4 + (size_t)WPACK_SHORTS*2)

typedef __attribute__((ext_vector_type(8))) short short8v;
typedef __attribute__((ext_vector_type(4))) float f32x4;

static __device__ __forceinline__ unsigned short bf16_rne(float f) {
    unsigned int b = __float_as_uint(f);
    return (unsigned short)((b + 0x7FFFu + ((b >> 16) & 1u)) >> 16);
}
static __device__ __forceinline__ float bf16_back(unsigned short h) {
    return __uint_as_float(((unsigned int)h) << 16);
}

// ================= wprep: pack weights into A-fragment order (bf16) ==========
// wpack[((oct*20 + gks)*64 + lane)*8 + j] = bf16(W[oct*16 + lane%16]
//        [chunk*144 + (gks%5)*32 + (lane/16)*8 + j]), zero when kk>=144.
__global__ __launch_bounds__(512) void dcn_wprep(
    const float* __restrict__ weight, short* __restrict__ wpack)
{
    const int g = blockIdx.x * 512 + threadIdx.x;      // 10 blocks -> 5120 groups
    const int oct = g / 1280;
    const int rem = g - oct * 1280;
    const int gks = rem >> 6;
    const int l   = rem & 63;
    const int chunk = gks / 5;
    const int kk    = (gks % 5) * 32 + ((l >> 4) & 3) * 8;
    const int oc    = oct * 16 + (l & 15);

    short8v v;
    if (kk < 144) {
        const float* src = weight + oc * 576 + chunk * 144 + kk;
#pragma unroll
        for (int j = 0; j < 8; ++j) v[j] = (short)bf16_rne(src[j]);
    } else {
#pragma unroll
        for (int j = 0; j < 8; ++j) v[j] = 0;
    }
    ((short8v*)wpack)[g] = v;
}

// ============================ K1: offset conv + sampling params ===============
__global__ __launch_bounds__(256, 2) void dcn_k1(
    const float* __restrict__ x,
    const float* __restrict__ w_off,
    const float* __restrict__ b_off,
    float* __restrict__ pwbuf,
    int*   __restrict__ abuf)
{
    __shared__ float lds[4 * 64 * OFFCn];   // 27.6 KB

    const int tid  = threadIdx.x;
    const int lane = tid & 63;
    const int wv   = tid >> 6;
    const int cbase = __builtin_amdgcn_readfirstlane(wv * 16);

    const int p  = blockIdx.x * 64 + lane;
    const int b  = p / HWn;
    const int hw = p % HWn;
    const int ho = hw / Wn;
    const int wo = hw % Wn;

    const float* xb = x + b * (Cn * HWn);

    int   toff[Kn];
    float tval[Kn];
#pragma unroll
    for (int ki = 0; ki < Kn; ++ki) {
        const int yy = ho + ki / 3 - 1, xx = wo + ki % 3 - 1;
        const bool v = (yy >= 0) && (yy < Hn) && (xx >= 0) && (xx < Wn);
        toff[ki] = min(max(yy, 0), Hn - 1) * Wn + min(max(xx, 0), Wn - 1);
        tval[ki] = v ? 1.0f : 0.0f;
    }

    float om[OFFCn];
#pragma unroll
    for (int j = 0; j < OFFCn; ++j) om[j] = 0.0f;

    for (int ci = 0; ci < 16; ++ci) {
        const int c = cbase + ci;
        const float* xc = xb + c * HWn;
        float xk[Kn];
#pragma unroll
        for (int ki = 0; ki < Kn; ++ki)
            xk[ki] = xc[toff[ki]] * tval[ki];

        const float* wc = w_off + c * Kn;
#pragma unroll
        for (int och = 0; och < OFFCn; ++och) {
            const float* wp = wc + och * (Cn * Kn);
            float a = om[och];
#pragma unroll
            for (int ki = 0; ki < Kn; ++ki)
                a = fmaf(xk[ki], wp[ki], a);
            om[och] = a;
        }
    }

#pragma unroll
    for (int j = 0; j < OFFCn; ++j)
        lds[(wv * 64 + lane) * OFFCn + j] = om[j];
    __syncthreads();
#pragma unroll
    for (int j = 0; j < OFFCn; ++j) {
        float a = b_off[j];
#pragma unroll
        for (int ww = 0; ww < 4; ++ww)
            a += lds[(ww * 64 + lane) * OFFCn + j];
        om[j] = a;
    }

    float pw0[Kn], pw1[Kn], pw2[Kn], pw3[Kn];
    int   pav[Kn];
#pragma unroll
    for (int ki = 0; ki < Kn; ++ki) {
        const float py = om[ki]      + (float)(ki / 3 + ho - 1);
        const float px = om[Kn + ki] + (float)(ki % 3 + wo - 1);
        const float m  = 1.0f / (1.0f + __expf(-om[2 * Kn + ki]));

        const float y0f = floorf(py), x0f = floorf(px);
        const float ly = py - y0f, lx = px - x0f;
        const int iy0 = (int)y0f, ix0 = (int)x0f;
        const int iy1 = iy0 + 1,  ix1 = ix0 + 1;

        const float vy0 = (iy0 >= 0 && iy0 < Hn) ? 1.0f : 0.0f;
        const float vy1 = (iy1 >= 0 && iy1 < Hn) ? 1.0f : 0.0f;
        const float vx0 = (ix0 >= 0 && ix0 < Wn) ? 1.0f : 0.0f;
        const float vx1 = (ix1 >= 0 && ix1 < Wn) ? 1.0f : 0.0f;

        const int iy0c = min(max(iy0, 0), Hn - 1);
        const int iy1c = min(max(iy1, 0), Hn - 1);
        const int ix0c = min(max(ix0, 0), Wn - 1);
        const int ix1c = min(max(ix1, 0), Wn - 1);

        pw0[ki] = m * (1.0f - ly) * (1.0f - lx) * vy0 * vx0;
        pw1[ki] = m * (1.0f - ly) * lx          * vy0 * vx1;
        pw2[ki] = m * ly          * (1.0f - lx) * vy1 * vx0;
        pw3[ki] = m * ly          * lx          * vy1 * vx1;
        const int pa  = iy0c * Wn + ix0c;
        const int dx  = ix1c - ix0c;
        const int dyw = (iy1c - iy0c) * Wn;
        pav[ki] = pa | (dx << 16) | (dyw << 17);
    }

    if (wv == 0) {
#pragma unroll
        for (int ki = 0; ki < Kn; ++ki) pwbuf[(0 * Kn + ki) * NPIX + p] = pw0[ki];
#pragma unroll
        for (int ki = 0; ki < Kn; ++ki) abuf[ki * NPIX + p] = pav[ki];
    } else if (wv == 1) {
#pragma unroll
        for (int ki = 0; ki < Kn; ++ki) pwbuf[(1 * Kn + ki) * NPIX + p] = pw1[ki];
    } else if (wv == 2) {
#pragma unroll
        for (int ki = 0; ki < Kn; ++ki) pwbuf[(2 * Kn + ki) * NPIX + p] = pw2[ki];
    } else {
#pragma unroll
        for (int ki = 0; ki < Kn; ++ki) pwbuf[(3 * Kn + ki) * NPIX + p] = pw3[ki];
    }
}

// ====== K2: gather -> split-bf16 LDS -> MFMA contraction ======================
// 8 waves: wave w = (pxt = w&3, plane = w>>2). 4 chunks of 16 c (144 k + 16 pad
// = 5 k-steps of 32). smp[k][66 px] bf16, 66-pad => conflict-free ds ops.
// A-frags from prepacked wpack (global/L2, coalesced 16B/lane).
#define SMP_PITCH 66
#define SMP_U16   (160 * SMP_PITCH)        // 10560 u16 per plane
__global__ __launch_bounds__(512, 4) void dcn_k2(
    const float* __restrict__ x,
    const short* __restrict__ wpack,
    const float* __restrict__ bias,
    const float* __restrict__ pwbuf,
    const int*   __restrict__ abuf,
    float* __restrict__ out)
{
    __shared__ unsigned short smp[2 * SMP_U16];      // 42240 B; reused as creduce

    const int tid  = threadIdx.x;
    const int lane = tid & 63;
    const int w    = tid >> 6;                 // 0..7
    const int pxt  = w & 3;
    const int plane= w >> 2;

    const int p0  = blockIdx.x * 64;           // block-uniform
    const int b   = p0 / HWn;
    const int hwb = p0 % HWn;
    const int p   = p0 + lane;

    const float* xb = x + b * (Cn * HWn);

    // per-pixel sampling params (px = lane)
    float pw0[Kn], pw1[Kn], pw2[Kn], pw3[Kn];
    int   pav[Kn];
#pragma unroll
    for (int ki = 0; ki < Kn; ++ki) pw0[ki] = pwbuf[(0 * Kn + ki) * NPIX + p];
#pragma unroll
    for (int ki = 0; ki < Kn; ++ki) pw1[ki] = pwbuf[(1 * Kn + ki) * NPIX + p];
#pragma unroll
    for (int ki = 0; ki < Kn; ++ki) pw2[ki] = pwbuf[(2 * Kn + ki) * NPIX + p];
#pragma unroll
    for (int ki = 0; ki < Kn; ++ki) pw3[ki] = pwbuf[(3 * Kn + ki) * NPIX + p];
#pragma unroll
    for (int ki = 0; ki < Kn; ++ki) pav[ki] = abuf[ki * NPIX + p];

    // zero the k-pad rows (144..159) once; first gather barrier covers it
    {
        unsigned int* zh = (unsigned int*)(smp + 144 * SMP_PITCH);
        unsigned int* zl = (unsigned int*)(smp + SMP_U16 + 144 * SMP_PITCH);
        for (int idx = tid; idx < (16 * SMP_PITCH) / 2; idx += 512) {
            zh[idx] = 0u; zl[idx] = 0u;
        }
    }

    f32x4 acc[4];
#pragma unroll
    for (int oct = 0; oct < 4; ++oct) acc[oct] = (f32x4){0.f, 0.f, 0.f, 0.f};

    unsigned short* smpP = smp + plane * SMP_U16;    // this wave's read plane
    const short8v* wfrag = (const short8v*)wpack;

    for (int chunk = 0; chunk < 4; ++chunk) {
        // ---- gather: wave w samples channels chunk*16 + w*2 + {0,1} ----
#pragma unroll
        for (int cc = 0; cc < 2; ++cc) {
            const int cin = (w << 1) | cc;                  // 0..15
            const float* xc = xb + (chunk * 16 + cin) * HWn;
#pragma unroll
            for (int ki = 0; ki < Kn; ++ki) {
                const int av  = pav[ki];
                const int pa  = av & 0xFFFF;
                const int dx  = (av >> 16) & 1;
                const int dyw = av >> 17;
                const float* bp = xc + pa;
                const float v = pw0[ki] * bp[0] + pw1[ki] * bp[dx]
                              + pw2[ki] * bp[dyw] + pw3[ki] * bp[dyw + dx];
                const unsigned short hb = bf16_rne(v);
                const unsigned short lb = bf16_rne(v - bf16_back(hb));
                const int k = cin * Kn + ki;                // 0..143
                smp[k * SMP_PITCH + lane]            = hb;
                smp[SMP_U16 + k * SMP_PITCH + lane]  = lb;
            }
        }
        __syncthreads();

        // ---- MFMA: 5 k-steps x 4 oc-tiles, this wave's (pxt, plane) ----
#pragma unroll
        for (int ks = 0; ks < 5; ++ks) {
            short8v av0 = wfrag[((0 * 20) + chunk * 5 + ks) * 64 + lane];
            short8v av1 = wfrag[((1 * 20) + chunk * 5 + ks) * 64 + lane];
            short8v av2 = wfrag[((2 * 20) + chunk * 5 + ks) * 64 + lane];
            short8v av3 = wfrag[((3 * 20) + chunk * 5 + ks) * 64 + lane];

            short8v bv;
            const int kb = ks * 32 + ((lane >> 4) & 3) * 8;
            const int pxl = pxt * 16 + (lane & 15);
#pragma unroll
            for (int j = 0; j < 8; ++j)
                bv[j] = (short)smpP[(kb + j) * SMP_PITCH + pxl];

            acc[0] = __builtin_amdgcn_mfma_f32_16x16x32_bf16(av0, bv, acc[0], 0, 0, 0);
            acc[1] = __builtin_amdgcn_mfma_f32_16x16x32_bf16(av1, bv, acc[1], 0, 0, 0);
            acc[2] = __builtin_amdgcn_mfma_f32_16x16x32_bf16(av2, bv, acc[2], 0, 0, 0);
            acc[3] = __builtin_amdgcn_mfma_f32_16x16x32_bf16(av3, bv, acc[3], 0, 0, 0);
        }
        __syncthreads();   // before next gather overwrites smp
    }

    // ---- merge planes via LDS, add bias, store ----
    float* cred = (float*)smp;     // [64 oc][66] fp32 = 16.9 KB (post-barrier)
    const int rbase = ((lane >> 4) & 3) * 4;       // C/D row group
    const int pxl   = pxt * 16 + (lane & 15);
    if (plane == 1) {
#pragma unroll
        for (int oct = 0; oct < 4; ++oct)
#pragma unroll
            for (int r = 0; r < 4; ++r)
                cred[(oct * 16 + rbase + r) * SMP_PITCH + pxl] = acc[oct][r];
    }
    __syncthreads();
    if (plane == 0) {
        float* ob = out + b * (OCn * HWn) + hwb + pxl;
#pragma unroll
        for (int oct = 0; oct < 4; ++oct) {
#pragma unroll
            for (int r = 0; r < 4; ++r) {
                const int oc = oct * 16 + rbase + r;
                const float v = acc[oct][r]
                              + cred[oc * SMP_PITCH + pxl] + bias[oc];
                ob[oc * HWn] = v;
            }
        }
    }
}

// ============================ fallback (R1 single-kernel, if ws too small) ====
__global__ __launch_bounds__(64) void dcn_r1(
    const float* __restrict__ x,
    const float* __restrict__ w_off,
    const float* __restrict__ b_off,
    const float* __restrict__ weight,
    const float* __restrict__ bias,
    float* __restrict__ out)
{
    const int p  = blockIdx.x * 64 + threadIdx.x;
    const int b  = p / HWn;
    const int hw = p % HWn;
    const int ho = hw / Wn;
    const int wo = hw % Wn;
    const float* xb = x + b * (Cn * HWn);

    float om[OFFCn];
#pragma unroll
    for (int j = 0; j < OFFCn; ++j) om[j] = b_off[j];

    int   toff[Kn];
    float tval[Kn];
#pragma unroll
    for (int ki = 0; ki < Kn; ++ki) {
        const int yy = ho + ki / 3 - 1, xx = wo + ki % 3 - 1;
        const bool v = (yy >= 0) && (yy < Hn) && (xx >= 0) && (xx < Wn);
        toff[ki] = min(max(yy, 0), Hn - 1) * Wn + min(max(xx, 0), Wn - 1);
        tval[ki] = v ? 1.0f : 0.0f;
    }
    for (int c = 0; c < Cn; ++c) {
        const float* xc = xb + c * HWn;
        float xk[Kn];
#pragma unroll
        for (int ki = 0; ki < Kn; ++ki) xk[ki] = xc[toff[ki]] * tval[ki];
        const float* wc = w_off + c * Kn;
#pragma unroll
        for (int och = 0; och < OFFCn; ++och) {
            const float* wp = wc + och * (Cn * Kn);
            float a = om[och];
#pragma unroll
            for (int ki = 0; ki < Kn; ++ki) a = fmaf(xk[ki], wp[ki], a);
            om[och] = a;
        }
    }
    float pw0[Kn], pw1[Kn], pw2[Kn], pw3[Kn];
    int   pa[Kn], pdx[Kn], pdyw[Kn];
#pragma unroll
    for (int ki = 0; ki < Kn; ++ki) {
        const float py = om[ki]      + (float)(ki / 3 + ho - 1);
        const float px = om[Kn + ki] + (float)(ki % 3 + wo - 1);
        const float m  = 1.0f / (1.0f + __expf(-om[2 * Kn + ki]));
        const float y0f = floorf(py), x0f = floorf(px);
        const float ly = py - y0f, lx = px - x0f;
        const int iy0 = (int)y0f, ix0 = (int)x0f;
        const int iy1 = iy0 + 1,  ix1 = ix0 + 1;
        const float vy0 = (iy0 >= 0 && iy0 < Hn) ? 1.0f : 0.0f;
        const float vy1 = (iy1 >= 0 && iy1 < Hn) ? 1.0f : 0.0f;
        const float vx0 = (ix0 >= 0 && ix0 < Wn) ? 1.0f : 0.0f;
        const float vx1 = (ix1 >= 0 && ix1 < Wn) ? 1.0f : 0.0f;
        const int iy0c = min(max(iy0, 0), Hn - 1);
        const int iy1c = min(max(iy1, 0), Hn - 1);
        const int ix0c = min(max(ix0, 0), Wn - 1);
        const int ix1c = min(max(ix1, 0), Wn - 1);
        pw0[ki] = m * (1.0f - ly) * (1.0f - lx) * vy0 * vx0;
        pw1[ki] = m * (1.0f - ly) * lx          * vy0 * vx1;
        pw2[ki] = m * ly          * (1.0f - lx) * vy1 * vx0;
        pw3[ki] = m * ly          * lx          * vy1 * vx1;
        pa[ki]   = iy0c * Wn + ix0c;
        pdx[ki]  = ix1c - ix0c;
        pdyw[ki] = (iy1c - iy0c) * Wn;
    }
    float acc[OCn];
#pragma unroll
    for (int oc = 0; oc < OCn; ++oc) acc[oc] = bias[oc];
    for (int c = 0; c < Cn; ++c) {
        const float* xc = xb + c * HWn;
        float s[Kn];
#pragma unroll
        for (int ki = 0; ki < Kn; ++ki) {
            const float* bp = xc + pa[ki];
            s[ki] = pw0[ki] * bp[0] + pw1[ki] * bp[pdx[ki]]
                  + pw2[ki] * bp[pdyw[ki]] + pw3[ki] * bp[pdyw[ki] + pdx[ki]];
        }
        const float* wc = weight + c * Kn;
#pragma unroll
        for (int oc = 0; oc < OCn; ++oc) {
            const float* wp = wc + oc * (Cn * Kn);
            float a = acc[oc];
#pragma unroll
            for (int ki = 0; ki < Kn; ++ki) a = fmaf(s[ki], wp[ki], a);
            acc[oc] = a;
        }
    }
    float* ob = out + b * (OCn * HWn) + hw;
#pragma unroll
    for (int oc = 0; oc < OCn; ++oc) ob[oc * HWn] = acc[oc];
}

extern "C" void kernel_launch(void* const* d_in, const int* in_sizes, int n_in,
                              void* d_out, int out_size, void* d_ws, size_t ws_size,
                              hipStream_t stream) {
    const float* x      = (const float*)d_in[0];
    const float* w_off  = (const float*)d_in[1];
    const float* b_off  = (const float*)d_in[2];
    const float* weight = (const float*)d_in[3];
    const float* bias   = (const float*)d_in[4];
    float* out = (float*)d_out;

    if (ws_size >= WS_BYTES) {
        float* pwbuf = (float*)d_ws;
        int*   abuf  = (int*)((float*)d_ws + 36 * NPIX);
        short* wpack = (short*)((float*)d_ws + WS_PARAM_DWORDS);
        hipLaunchKernelGGL(dcn_wprep, dim3(10), dim3(512), 0, stream,
                           weight, wpack);
        hipLaunchKernelGGL(dcn_k1, dim3(PGRPS), dim3(256), 0, stream,
                           x, w_off, b_off, pwbuf, abuf);
        hipLaunchKernelGGL(dcn_k2, dim3(PGRPS), dim3(512), 0, stream,
                           x, wpack, bias, pwbuf, abuf, out);
    } else {
        hipLaunchKernelGGL(dcn_r1, dim3(NPIX / 64), dim3(64), 0, stream,
                           x, w_off, b_off, weight, bias, out);
    }
}

// Round 9
// 312.072 us; speedup vs baseline: 1.3421x; 1.3421x over previous
//
#include <hip/hip_runtime.h>
#include <math.h>

#define Bn 8
#define Cn 64
#define Hn 96
#define Wn 96
#define HWn (Hn*Wn)
#define OCn 64
#define Kn 9
#define OFFCn 27
#define NPIX (Bn*HWn)        // 73728 = 1152*64
#define PGRPS (NPIX/64)      // 1152 pixel groups

// ws: float pwbuf[36][NPIX]; int abuf[9][NPIX]; int counters[2]
#define WS_DWORDS (45*NPIX + 2)
#define WS_BYTES  ((size_t)WS_DWORDS*4)

// ============================ reset: zero the ticket counters =================
__global__ void dcn_reset(int* __restrict__ cnt) {
    if (threadIdx.x < 2) cnt[threadIdx.x] = 0;
}

// ============================ K1: offset conv + sampling params ===============
// Persistent: 1024 blocks x 4 waves, ticket-loop over 1152 pixel groups.
__global__ __launch_bounds__(256, 4) void dcn_k1(
    const float* __restrict__ x,
    const float* __restrict__ w_off,
    const float* __restrict__ b_off,
    float* __restrict__ pwbuf,
    int*   __restrict__ abuf,
    int*   __restrict__ cnt)
{
    __shared__ float lds[4 * 64 * OFFCn];   // 27.6 KB
    __shared__ int sh_g;

    const int tid  = threadIdx.x;
    const int lane = tid & 63;
    const int wv   = tid >> 6;
    const int cbase = __builtin_amdgcn_readfirstlane(wv * 16);

    for (;;) {
        if (tid == 0) sh_g = atomicAdd(cnt, 1);
        __syncthreads();
        const int grp = sh_g;
        if (grp >= PGRPS) break;

        const int p  = grp * 64 + lane;
        const int b  = p / HWn;
        const int hw = p % HWn;
        const int ho = hw / Wn;
        const int wo = hw % Wn;

        const float* xb = x + b * (Cn * HWn);

        // static 3x3 taps, zero-pad via multiply (branchless, uniform CF)
        int   toff[Kn];
        float tval[Kn];
#pragma unroll
        for (int ki = 0; ki < Kn; ++ki) {
            const int yy = ho + ki / 3 - 1, xx = wo + ki % 3 - 1;
            const bool v = (yy >= 0) && (yy < Hn) && (xx >= 0) && (xx < Wn);
            toff[ki] = min(max(yy, 0), Hn - 1) * Wn + min(max(xx, 0), Wn - 1);
            tval[ki] = v ? 1.0f : 0.0f;
        }

        // offset conv partial over 16 channels per wave
        float om[OFFCn];
#pragma unroll
        for (int j = 0; j < OFFCn; ++j) om[j] = 0.0f;

        for (int ci = 0; ci < 16; ++ci) {
            const int c = cbase + ci;
            const float* xc = xb + c * HWn;
            float xk[Kn];
#pragma unroll
            for (int ki = 0; ki < Kn; ++ki)
                xk[ki] = xc[toff[ki]] * tval[ki];

            const float* wc = w_off + c * Kn;
#pragma unroll
            for (int och = 0; och < OFFCn; ++och) {
                const float* wp = wc + och * (Cn * Kn);
                float a = om[och];
#pragma unroll
                for (int ki = 0; ki < Kn; ++ki)
                    a = fmaf(xk[ki], wp[ki], a);
                om[och] = a;
            }
        }

        // LDS reduce (stride 27, gcd(27,32)=1 -> conflict-free)
#pragma unroll
        for (int j = 0; j < OFFCn; ++j)
            lds[(wv * 64 + lane) * OFFCn + j] = om[j];
        __syncthreads();
#pragma unroll
        for (int j = 0; j < OFFCn; ++j) {
            float a = b_off[j];
#pragma unroll
            for (int ww = 0; ww < 4; ++ww)
                a += lds[(ww * 64 + lane) * OFFCn + j];
            om[j] = a;
        }

        // per-k sampling params
        float pw0[Kn], pw1[Kn], pw2[Kn], pw3[Kn];
        int   pav[Kn];
#pragma unroll
        for (int ki = 0; ki < Kn; ++ki) {
            const float py = om[ki]      + (float)(ki / 3 + ho - 1);
            const float px = om[Kn + ki] + (float)(ki % 3 + wo - 1);
            const float m  = 1.0f / (1.0f + __expf(-om[2 * Kn + ki]));

            const float y0f = floorf(py), x0f = floorf(px);
            const float ly = py - y0f, lx = px - x0f;
            const int iy0 = (int)y0f, ix0 = (int)x0f;
            const int iy1 = iy0 + 1,  ix1 = ix0 + 1;

            const float vy0 = (iy0 >= 0 && iy0 < Hn) ? 1.0f : 0.0f;
            const float vy1 = (iy1 >= 0 && iy1 < Hn) ? 1.0f : 0.0f;
            const float vx0 = (ix0 >= 0 && ix0 < Wn) ? 1.0f : 0.0f;
            const float vx1 = (ix1 >= 0 && ix1 < Wn) ? 1.0f : 0.0f;

            const int iy0c = min(max(iy0, 0), Hn - 1);
            const int iy1c = min(max(iy1, 0), Hn - 1);
            const int ix0c = min(max(ix0, 0), Wn - 1);
            const int ix1c = min(max(ix1, 0), Wn - 1);

            pw0[ki] = m * (1.0f - ly) * (1.0f - lx) * vy0 * vx0;
            pw1[ki] = m * (1.0f - ly) * lx          * vy0 * vx1;
            pw2[ki] = m * ly          * (1.0f - lx) * vy1 * vx0;
            pw3[ki] = m * ly          * lx          * vy1 * vx1;
            const int pa  = iy0c * Wn + ix0c;        // fits 16 bits
            const int dx  = ix1c - ix0c;             // 0/1
            const int dyw = (iy1c - iy0c) * Wn;      // 0/96
            pav[ki] = pa | (dx << 16) | (dyw << 17);
        }

        if (wv == 0) {
#pragma unroll
            for (int ki = 0; ki < Kn; ++ki) pwbuf[(0 * Kn + ki) * NPIX + p] = pw0[ki];
#pragma unroll
            for (int ki = 0; ki < Kn; ++ki) abuf[ki * NPIX + p] = pav[ki];
        } else if (wv == 1) {
#pragma unroll
            for (int ki = 0; ki < Kn; ++ki) pwbuf[(1 * Kn + ki) * NPIX + p] = pw1[ki];
        } else if (wv == 2) {
#pragma unroll
            for (int ki = 0; ki < Kn; ++ki) pwbuf[(2 * Kn + ki) * NPIX + p] = pw2[ki];
        } else {
#pragma unroll
            for (int ki = 0; ki < Kn; ++ki) pwbuf[(3 * Kn + ki) * NPIX + p] = pw3[ki];
        }
        __syncthreads();   // protect lds + sh_g before next iteration
    }
}

// ====== K2: persistent 8-wave, LDS-shared sampling + 8-way oc-split ===========
__global__ __launch_bounds__(512, 4) void dcn_k2(
    const float* __restrict__ x,
    const float* __restrict__ weight,
    const float* __restrict__ bias,
    const float* __restrict__ pwbuf,
    const int*   __restrict__ abuf,
    int*   __restrict__ cnt,
    float* __restrict__ out)
{
    __shared__ float smp[8 * Kn * 64];   // [c8][ki][pix] = 18.4 KB
    __shared__ int sh_g;

    const int tid  = threadIdx.x;
    const int lane = tid & 63;
    const int wv   = tid >> 6;                                 // 0..7
    const int ocb  = __builtin_amdgcn_readfirstlane(wv * 8);   // 0,8,..,56

    for (;;) {
        if (tid == 0) sh_g = atomicAdd(cnt + 1, 1);
        __syncthreads();
        const int grp = sh_g;
        if (grp >= PGRPS) break;

        const int p  = grp * 64 + lane;
        const int b  = p / HWn;
        const int hw = p % HWn;

        const float* xb = x + b * (Cn * HWn);

        // load params (coalesced dword streams); addresses kept packed
        float pw0[Kn], pw1[Kn], pw2[Kn], pw3[Kn];
        int   pav[Kn];
#pragma unroll
        for (int ki = 0; ki < Kn; ++ki) pw0[ki] = pwbuf[(0 * Kn + ki) * NPIX + p];
#pragma unroll
        for (int ki = 0; ki < Kn; ++ki) pw1[ki] = pwbuf[(1 * Kn + ki) * NPIX + p];
#pragma unroll
        for (int ki = 0; ki < Kn; ++ki) pw2[ki] = pwbuf[(2 * Kn + ki) * NPIX + p];
#pragma unroll
        for (int ki = 0; ki < Kn; ++ki) pw3[ki] = pwbuf[(3 * Kn + ki) * NPIX + p];
#pragma unroll
        for (int ki = 0; ki < Kn; ++ki) pav[ki] = abuf[ki * NPIX + p];

        float acc[8];
#pragma unroll
        for (int j = 0; j < 8; ++j) acc[j] = bias[ocb + j];

        for (int ch = 0; ch < 8; ++ch) {
            // gather: wave wv samples channel ch*8 + wv for its pixel
            {
                const float* xc = xb + (ch * 8 + wv) * HWn;
#pragma unroll
                for (int ki = 0; ki < Kn; ++ki) {
                    const int av  = pav[ki];
                    const int pa  = av & 0xFFFF;
                    const int dx  = (av >> 16) & 1;
                    const int dyw = av >> 17;
                    const float* bp = xc + pa;
                    const float v00 = bp[0];
                    const float v01 = bp[dx];
                    const float v10 = bp[dyw];
                    const float v11 = bp[dyw + dx];
                    smp[(wv * Kn + ki) * 64 + lane] =
                        pw0[ki] * v00 + pw1[ki] * v01 + pw2[ki] * v10 + pw3[ki] * v11;
                }
            }
            __syncthreads();

            const float* wch = weight + (ocb * Cn + ch * 8) * Kn;   // wave-uniform
#pragma unroll 2
            for (int c8 = 0; c8 < 8; ++c8) {
                float sv[Kn];
#pragma unroll
                for (int ki = 0; ki < Kn; ++ki)
                    sv[ki] = smp[(c8 * Kn + ki) * 64 + lane];
#pragma unroll
                for (int j = 0; j < 8; ++j) {
                    const float* wp = wch + j * (Cn * Kn) + c8 * Kn;
                    float a = acc[j];
#pragma unroll
                    for (int ki = 0; ki < Kn; ++ki)
                        a = fmaf(sv[ki], wp[ki], a);
                    acc[j] = a;
                }
            }
            __syncthreads();
        }

        float* ob = out + b * (OCn * HWn) + hw;
#pragma unroll
        for (int j = 0; j < 8; ++j)
            ob[(ocb + j) * HWn] = acc[j];
        // no extra barrier needed: next iteration starts with ticket+barrier
    }
}

// ============================ fallback (R1 single-kernel, if ws too small) ====
__global__ __launch_bounds__(64) void dcn_r1(
    const float* __restrict__ x,
    const float* __restrict__ w_off,
    const float* __restrict__ b_off,
    const float* __restrict__ weight,
    const float* __restrict__ bias,
    float* __restrict__ out)
{
    const int p  = blockIdx.x * 64 + threadIdx.x;
    const int b  = p / HWn;
    const int hw = p % HWn;
    const int ho = hw / Wn;
    const int wo = hw % Wn;
    const float* xb = x + b * (Cn * HWn);

    float om[OFFCn];
#pragma unroll
    for (int j = 0; j < OFFCn; ++j) om[j] = b_off[j];

    int   toff[Kn];
    float tval[Kn];
#pragma unroll
    for (int ki = 0; ki < Kn; ++ki) {
        const int yy = ho + ki / 3 - 1, xx = wo + ki % 3 - 1;
        const bool v = (yy >= 0) && (yy < Hn) && (xx >= 0) && (xx < Wn);
        toff[ki] = min(max(yy, 0), Hn - 1) * Wn + min(max(xx, 0), Wn - 1);
        tval[ki] = v ? 1.0f : 0.0f;
    }
    for (int c = 0; c < Cn; ++c) {
        const float* xc = xb + c * HWn;
        float xk[Kn];
#pragma unroll
        for (int ki = 0; ki < Kn; ++ki) xk[ki] = xc[toff[ki]] * tval[ki];
        const float* wc = w_off + c * Kn;
#pragma unroll
        for (int och = 0; och < OFFCn; ++och) {
            const float* wp = wc + och * (Cn * Kn);
            float a = om[och];
#pragma unroll
            for (int ki = 0; ki < Kn; ++ki) a = fmaf(xk[ki], wp[ki], a);
            om[och] = a;
        }
    }
    float pw0[Kn], pw1[Kn], pw2[Kn], pw3[Kn];
    int   pa[Kn], pdx[Kn], pdyw[Kn];
#pragma unroll
    for (int ki = 0; ki < Kn; ++ki) {
        const float py = om[ki]      + (float)(ki / 3 + ho - 1);
        const float px = om[Kn + ki] + (float)(ki % 3 + wo - 1);
        const float m  = 1.0f / (1.0f + __expf(-om[2 * Kn + ki]));
        const float y0f = floorf(py), x0f = floorf(px);
        const float ly = py - y0f, lx = px - x0f;
        const int iy0 = (int)y0f, ix0 = (int)x0f;
        const int iy1 = iy0 + 1,  ix1 = ix0 + 1;
        const float vy0 = (iy0 >= 0 && iy0 < Hn) ? 1.0f : 0.0f;
        const float vy1 = (iy1 >= 0 && iy1 < Hn) ? 1.0f : 0.0f;
        const float vx0 = (ix0 >= 0 && ix0 < Wn) ? 1.0f : 0.0f;
        const float vx1 = (ix1 >= 0 && ix1 < Wn) ? 1.0f : 0.0f;
        const int iy0c = min(max(iy0, 0), Hn - 1);
        const int iy1c = min(max(iy1, 0), Hn - 1);
        const int ix0c = min(max(ix0, 0), Wn - 1);
        const int ix1c = min(max(ix1, 0), Wn - 1);
        pw0[ki] = m * (1.0f - ly) * (1.0f - lx) * vy0 * vx0;
        pw1[ki] = m * (1.0f - ly) * lx          * vy0 * vx1;
        pw2[ki] = m * ly          * (1.0f - lx) * vy1 * vx0;
        pw3[ki] = m * ly          * lx          * vy1 * vx1;
        pa[ki]   = iy0c * Wn + ix0c;
        pdx[ki]  = ix1c - ix0c;
        pdyw[ki] = (iy1c - iy0c) * Wn;
    }
    float acc[OCn];
#pragma unroll
    for (int oc = 0; oc < OCn; ++oc) acc[oc] = bias[oc];
    for (int c = 0; c < Cn; ++c) {
        const float* xc = xb + c * HWn;
        float s[Kn];
#pragma unroll
        for (int ki = 0; ki < Kn; ++ki) {
            const float* bp = xc + pa[ki];
            s[ki] = pw0[ki] * bp[0] + pw1[ki] * bp[pdx[ki]]
                  + pw2[ki] * bp[pdyw[ki]] + pw3[ki] * bp[pdyw[ki] + pdx[ki]];
        }
        const float* wc = weight + c * Kn;
#pragma unroll
        for (int oc = 0; oc < OCn; ++oc) {
            const float* wp = wc + oc * (Cn * Kn);
            float a = acc[oc];
#pragma unroll
            for (int ki = 0; ki < Kn; ++ki) a = fmaf(s[ki], wp[ki], a);
            acc[oc] = a;
        }
    }
    float* ob = out + b * (OCn * HWn) + hw;
#pragma unroll
    for (int oc = 0; oc < OCn; ++oc) ob[oc * HWn] = acc[oc];
}

extern "C" void kernel_launch(void* const* d_in, const int* in_sizes, int n_in,
                              void* d_out, int out_size, void* d_ws, size_t ws_size,
                              hipStream_t stream) {
    const float* x      = (const float*)d_in[0];
    const float* w_off  = (const float*)d_in[1];
    const float* b_off  = (const float*)d_in[2];
    const float* weight = (const float*)d_in[3];
    const float* bias   = (const float*)d_in[4];
    float* out = (float*)d_out;

    if (ws_size >= WS_BYTES) {
        float* pwbuf = (float*)d_ws;
        int*   abuf  = (int*)((float*)d_ws + 36 * NPIX);
        int*   cnt   = (int*)((float*)d_ws + 45 * NPIX);
        hipLaunchKernelGGL(dcn_reset, dim3(1), dim3(64), 0, stream, cnt);
        hipLaunchKernelGGL(dcn_k1, dim3(1024), dim3(256), 0, stream,
                           x, w_off, b_off, pwbuf, abuf, cnt);
        hipLaunchKernelGGL(dcn_k2, dim3(1024), dim3(512), 0, stream,
                           x, weight, bias, pwbuf, abuf, cnt, out);
    } else {
        hipLaunchKernelGGL(dcn_r1, dim3(NPIX / 64), dim3(64), 0, stream,
                           x, w_off, b_off, weight, bias, out);
    }
}

// Round 10
// 256.731 us; speedup vs baseline: 1.6314x; 1.2156x over previous
//
#include <hip/hip_runtime.h>
#include <math.h>

#define Bn 8
#define Cn 64
#define Hn 96
#define Wn 96
#define HWn (Hn*Wn)
#define OCn 64
#define Kn 9
#define OFFCn 27
#define NPIX (Bn*HWn)        // 73728 = 1152*64
#define PGRPS (NPIX/64)      // 1152 pixel groups

// ws layout (dwords): pwbuf[36*NPIX] | abuf[9*NPIX] | wpk1[15552] | wpk2[36864]
#define WPK1_N 15552          // 64c * 27och * 9k   (K1 offset-conv weights, per-wave stream)
#define WPK2_N 36864          // 8wv * 4ch * 16c * 8oc * 9k (K2 weights, per-wave stream)
#define WS_DWORDS (45*NPIX + WPK1_N + WPK2_N)
#define WS_BYTES  ((size_t)WS_DWORDS*4)

// ============ wprep: permute weights into per-wave contiguous streams =========
__global__ __launch_bounds__(256) void dcn_wprep(
    const float* __restrict__ w_off,
    const float* __restrict__ weight,
    float* __restrict__ wpk1,
    float* __restrict__ wpk2)
{
    const int g = blockIdx.x * 256 + threadIdx.x;
    if (g < WPK1_N) {
        // wpk1[(c_all*27 + och)*9 + ki] = w_off[och][c_all][ki]
        const int c_all = g / 243;
        const int och   = (g % 243) / 9;
        const int ki    = g % 9;
        wpk1[g] = w_off[(och * 64 + c_all) * 9 + ki];
    }
    const int h = g - WPK1_N;
    if (h >= 0 && h < WPK2_N) {
        // wpk2[(((wv*4+ch)*16 + c16)*8 + j)*9 + ki] = weight[wv*8+j][ch*16+c16][ki]
        const int ki  = h % 9;
        const int j   = (h / 9) % 8;
        const int c16 = (h / 72) % 16;
        const int ch  = (h / 1152) % 4;
        const int wv  = h / 4608;
        const int oc  = wv * 8 + j;
        const int c   = ch * 16 + c16;
        wpk2[h] = weight[(oc * 64 + c) * 9 + ki];
    }
}

// ============================ K1: offset conv + sampling params ===============
__global__ __launch_bounds__(256, 2) void dcn_k1(
    const float* __restrict__ x,
    const float* __restrict__ wpk1,
    const float* __restrict__ b_off,
    float* __restrict__ pwbuf,
    int*   __restrict__ abuf)
{
    __shared__ float lds[4 * 64 * OFFCn];   // 27.6 KB

    const int tid  = threadIdx.x;
    const int lane = tid & 63;
    const int wv   = tid >> 6;
    const int cbase = __builtin_amdgcn_readfirstlane(wv * 16);

    const int p  = blockIdx.x * 64 + lane;
    const int b  = p / HWn;
    const int hw = p % HWn;
    const int ho = hw / Wn;
    const int wo = hw % Wn;

    const float* xb = x + b * (Cn * HWn);

    // static 3x3 taps, zero-pad via multiply (branchless, uniform CF)
    int   toff[Kn];
    float tval[Kn];
#pragma unroll
    for (int ki = 0; ki < Kn; ++ki) {
        const int yy = ho + ki / 3 - 1, xx = wo + ki % 3 - 1;
        const bool v = (yy >= 0) && (yy < Hn) && (xx >= 0) && (xx < Wn);
        toff[ki] = min(max(yy, 0), Hn - 1) * Wn + min(max(xx, 0), Wn - 1);
        tval[ki] = v ? 1.0f : 0.0f;
    }

    // offset conv partial over 16 channels; weights = CONTIGUOUS per-wave stream
    float om[OFFCn];
#pragma unroll
    for (int j = 0; j < OFFCn; ++j) om[j] = 0.0f;

    const float* wstream = wpk1 + cbase * 243;   // wave-uniform, sequential
    for (int ci = 0; ci < 16; ++ci) {
        const float* xc = xb + (cbase + ci) * HWn;
        float xk[Kn];
#pragma unroll
        for (int ki = 0; ki < Kn; ++ki)
            xk[ki] = xc[toff[ki]] * tval[ki];

        const float* wc = wstream + ci * 243;    // 243 contiguous dwords
#pragma unroll
        for (int och = 0; och < OFFCn; ++och) {
            const float* wp = wc + och * 9;
            float a = om[och];
#pragma unroll
            for (int ki = 0; ki < Kn; ++ki)
                a = fmaf(xk[ki], wp[ki], a);
            om[och] = a;
        }
    }

    // LDS reduce (stride 27, gcd(27,32)=1 -> conflict-free)
#pragma unroll
    for (int j = 0; j < OFFCn; ++j)
        lds[(wv * 64 + lane) * OFFCn + j] = om[j];
    __syncthreads();
#pragma unroll
    for (int j = 0; j < OFFCn; ++j) {
        float a = b_off[j];
#pragma unroll
        for (int ww = 0; ww < 4; ++ww)
            a += lds[(ww * 64 + lane) * OFFCn + j];
        om[j] = a;
    }

    // per-k sampling params (each wave computes redundantly; stores its slice)
    float pw0[Kn], pw1[Kn], pw2[Kn], pw3[Kn];
    int   pav[Kn];
#pragma unroll
    for (int ki = 0; ki < Kn; ++ki) {
        const float py = om[ki]      + (float)(ki / 3 + ho - 1);
        const float px = om[Kn + ki] + (float)(ki % 3 + wo - 1);
        const float m  = 1.0f / (1.0f + __expf(-om[2 * Kn + ki]));

        const float y0f = floorf(py), x0f = floorf(px);
        const float ly = py - y0f, lx = px - x0f;
        const int iy0 = (int)y0f, ix0 = (int)x0f;
        const int iy1 = iy0 + 1,  ix1 = ix0 + 1;

        const float vy0 = (iy0 >= 0 && iy0 < Hn) ? 1.0f : 0.0f;
        const float vy1 = (iy1 >= 0 && iy1 < Hn) ? 1.0f : 0.0f;
        const float vx0 = (ix0 >= 0 && ix0 < Wn) ? 1.0f : 0.0f;
        const float vx1 = (ix1 >= 0 && ix1 < Wn) ? 1.0f : 0.0f;

        const int iy0c = min(max(iy0, 0), Hn - 1);
        const int iy1c = min(max(iy1, 0), Hn - 1);
        const int ix0c = min(max(ix0, 0), Wn - 1);
        const int ix1c = min(max(ix1, 0), Wn - 1);

        pw0[ki] = m * (1.0f - ly) * (1.0f - lx) * vy0 * vx0;
        pw1[ki] = m * (1.0f - ly) * lx          * vy0 * vx1;
        pw2[ki] = m * ly          * (1.0f - lx) * vy1 * vx0;
        pw3[ki] = m * ly          * lx          * vy1 * vx1;
        const int pa  = iy0c * Wn + ix0c;        // fits 16 bits
        const int dx  = ix1c - ix0c;             // 0/1
        const int dyw = (iy1c - iy0c) * Wn;      // 0/96
        pav[ki] = pa | (dx << 16) | (dyw << 17);
    }

    if (wv == 0) {
#pragma unroll
        for (int ki = 0; ki < Kn; ++ki) pwbuf[(0 * Kn + ki) * NPIX + p] = pw0[ki];
#pragma unroll
        for (int ki = 0; ki < Kn; ++ki) abuf[ki * NPIX + p] = pav[ki];
    } else if (wv == 1) {
#pragma unroll
        for (int ki = 0; ki < Kn; ++ki) pwbuf[(1 * Kn + ki) * NPIX + p] = pw1[ki];
    } else if (wv == 2) {
#pragma unroll
        for (int ki = 0; ki < Kn; ++ki) pwbuf[(2 * Kn + ki) * NPIX + p] = pw2[ki];
    } else {
#pragma unroll
        for (int ki = 0; ki < Kn; ++ki) pwbuf[(3 * Kn + ki) * NPIX + p] = pw3[ki];
    }
}

// ====== K2: 8-wave, LDS-shared sampling (16c chunks) + 8-way oc-split =========
// Chunks of 16 channels: barriers 8/group (was 16). Weights from wpk2 stream:
// per (wave,chunk) 1152 CONTIGUOUS dwords -> s_load_dwordx16 chains, deep
// prefetch, no per-oc address gen.
__global__ __launch_bounds__(512, 4) void dcn_k2(
    const float* __restrict__ x,
    const float* __restrict__ wpk2,
    const float* __restrict__ bias,
    const float* __restrict__ pwbuf,
    const int*   __restrict__ abuf,
    float* __restrict__ out)
{
    __shared__ float smp[16 * Kn * 64];   // [c16][ki][pix] = 36.9 KB

    const int tid  = threadIdx.x;
    const int lane = tid & 63;
    const int wv   = tid >> 6;                                 // 0..7
    const int ocb  = __builtin_amdgcn_readfirstlane(wv * 8);   // 0,8,..,56

    const int p  = blockIdx.x * 64 + lane;
    const int b  = p / HWn;
    const int hw = p % HWn;

    const float* xb = x + b * (Cn * HWn);

    // load params (coalesced dword streams); addresses kept packed
    float pw0[Kn], pw1[Kn], pw2[Kn], pw3[Kn];
    int   pav[Kn];
#pragma unroll
    for (int ki = 0; ki < Kn; ++ki) pw0[ki] = pwbuf[(0 * Kn + ki) * NPIX + p];
#pragma unroll
    for (int ki = 0; ki < Kn; ++ki) pw1[ki] = pwbuf[(1 * Kn + ki) * NPIX + p];
#pragma unroll
    for (int ki = 0; ki < Kn; ++ki) pw2[ki] = pwbuf[(2 * Kn + ki) * NPIX + p];
#pragma unroll
    for (int ki = 0; ki < Kn; ++ki) pw3[ki] = pwbuf[(3 * Kn + ki) * NPIX + p];
#pragma unroll
    for (int ki = 0; ki < Kn; ++ki) pav[ki] = abuf[ki * NPIX + p];

    float acc[8];
#pragma unroll
    for (int j = 0; j < 8; ++j) acc[j] = bias[ocb + j];

    const float* wbase = wpk2 + __builtin_amdgcn_readfirstlane(wv * 4 * 1152);

    for (int ch = 0; ch < 4; ++ch) {
        // gather: wave wv samples channels ch*16 + wv*2 + {0,1} for its pixel
#pragma unroll
        for (int cc = 0; cc < 2; ++cc) {
            const int cin = (wv << 1) | cc;                  // 0..15
            const float* xc = xb + (ch * 16 + cin) * HWn;
#pragma unroll
            for (int ki = 0; ki < Kn; ++ki) {
                const int av  = pav[ki];
                const int pa  = av & 0xFFFF;
                const int dx  = (av >> 16) & 1;
                const int dyw = av >> 17;
                const float* bp = xc + pa;
                const float v00 = bp[0];
                const float v01 = bp[dx];
                const float v10 = bp[dyw];
                const float v11 = bp[dyw + dx];
                smp[(cin * Kn + ki) * 64 + lane] =
                    pw0[ki] * v00 + pw1[ki] * v01 + pw2[ki] * v10 + pw3[ki] * v11;
            }
        }
        __syncthreads();

        const float* ws2 = wbase + ch * 1152;    // contiguous stream this chunk
#pragma unroll 2
        for (int c16 = 0; c16 < 16; ++c16) {
            float sv[Kn];
#pragma unroll
            for (int ki = 0; ki < Kn; ++ki)
                sv[ki] = smp[(c16 * Kn + ki) * 64 + lane];
            const float* wc = ws2 + c16 * 72;
#pragma unroll
            for (int j = 0; j < 8; ++j) {
                const float* wp = wc + j * 9;
                float a = acc[j];
#pragma unroll
                for (int ki = 0; ki < Kn; ++ki)
                    a = fmaf(sv[ki], wp[ki], a);
                acc[j] = a;
            }
        }
        __syncthreads();
    }

    float* ob = out + b * (OCn * HWn) + hw;
#pragma unroll
    for (int j = 0; j < 8; ++j)
        ob[(ocb + j) * HWn] = acc[j];
}

// ============================ fallback (R1 single-kernel, if ws too small) ====
__global__ __launch_bounds__(64) void dcn_r1(
    const float* __restrict__ x,
    const float* __restrict__ w_off,
    const float* __restrict__ b_off,
    const float* __restrict__ weight,
    const float* __restrict__ bias,
    float* __restrict__ out)
{
    const int p  = blockIdx.x * 64 + threadIdx.x;
    const int b  = p / HWn;
    const int hw = p % HWn;
    const int ho = hw / Wn;
    const int wo = hw % Wn;
    const float* xb = x + b * (Cn * HWn);

    float om[OFFCn];
#pragma unroll
    for (int j = 0; j < OFFCn; ++j) om[j] = b_off[j];

    int   toff[Kn];
    float tval[Kn];
#pragma unroll
    for (int ki = 0; ki < Kn; ++ki) {
        const int yy = ho + ki / 3 - 1, xx = wo + ki % 3 - 1;
        const bool v = (yy >= 0) && (yy < Hn) && (xx >= 0) && (xx < Wn);
        toff[ki] = min(max(yy, 0), Hn - 1) * Wn + min(max(xx, 0), Wn - 1);
        tval[ki] = v ? 1.0f : 0.0f;
    }
    for (int c = 0; c < Cn; ++c) {
        const float* xc = xb + c * HWn;
        float xk[Kn];
#pragma unroll
        for (int ki = 0; ki < Kn; ++ki) xk[ki] = xc[toff[ki]] * tval[ki];
        const float* wc = w_off + c * Kn;
#pragma unroll
        for (int och = 0; och < OFFCn; ++och) {
            const float* wp = wc + och * (Cn * Kn);
            float a = om[och];
#pragma unroll
            for (int ki = 0; ki < Kn; ++ki) a = fmaf(xk[ki], wp[ki], a);
            om[och] = a;
        }
    }
    float pw0[Kn], pw1[Kn], pw2[Kn], pw3[Kn];
    int   pa[Kn], pdx[Kn], pdyw[Kn];
#pragma unroll
    for (int ki = 0; ki < Kn; ++ki) {
        const float py = om[ki]      + (float)(ki / 3 + ho - 1);
        const float px = om[Kn + ki] + (float)(ki % 3 + wo - 1);
        const float m  = 1.0f / (1.0f + __expf(-om[2 * Kn + ki]));
        const float y0f = floorf(py), x0f = floorf(px);
        const float ly = py - y0f, lx = px - x0f;
        const int iy0 = (int)y0f, ix0 = (int)x0f;
        const int iy1 = iy0 + 1,  ix1 = ix0 + 1;
        const float vy0 = (iy0 >= 0 && iy0 < Hn) ? 1.0f : 0.0f;
        const float vy1 = (iy1 >= 0 && iy1 < Hn) ? 1.0f : 0.0f;
        const float vx0 = (ix0 >= 0 && ix0 < Wn) ? 1.0f : 0.0f;
        const float vx1 = (ix1 >= 0 && ix1 < Wn) ? 1.0f : 0.0f;
        const int iy0c = min(max(iy0, 0), Hn - 1);
        const int iy1c = min(max(iy1, 0), Hn - 1);
        const int ix0c = min(max(ix0, 0), Wn - 1);
        const int ix1c = min(max(ix1, 0), Wn - 1);
        pw0[ki] = m * (1.0f - ly) * (1.0f - lx) * vy0 * vx0;
        pw1[ki] = m * (1.0f - ly) * lx          * vy0 * vx1;
        pw2[ki] = m * ly          * (1.0f - lx) * vy1 * vx0;
        pw3[ki] = m * ly          * lx          * vy1 * vx1;
        pa[ki]   = iy0c * Wn + ix0c;
        pdx[ki]  = ix1c - ix0c;
        pdyw[ki] = (iy1c - iy0c) * Wn;
    }
    float acc[OCn];
#pragma unroll
    for (int oc = 0; oc < OCn; ++oc) acc[oc] = bias[oc];
    for (int c = 0; c < Cn; ++c) {
        const float* xc = xb + c * HWn;
        float s[Kn];
#pragma unroll
        for (int ki = 0; ki < Kn; ++ki) {
            const float* bp = xc + pa[ki];
            s[ki] = pw0[ki] * bp[0] + pw1[ki] * bp[pdx[ki]]
                  + pw2[ki] * bp[pdyw[ki]] + pw3[ki] * bp[pdyw[ki] + pdx[ki]];
        }
        const float* wc = weight + c * Kn;
#pragma unroll
        for (int oc = 0; oc < OCn; ++oc) {
            const float* wp = wc + oc * (Cn * Kn);
            float a = acc[oc];
#pragma unroll
            for (int ki = 0; ki < Kn; ++ki) a = fmaf(s[ki], wp[ki], a);
            acc[oc] = a;
        }
    }
    float* ob = out + b * (OCn * HWn) + hw;
#pragma unroll
    for (int oc = 0; oc < OCn; ++oc) ob[oc * HWn] = acc[oc];
}

extern "C" void kernel_launch(void* const* d_in, const int* in_sizes, int n_in,
                              void* d_out, int out_size, void* d_ws, size_t ws_size,
                              hipStream_t stream) {
    const float* x      = (const float*)d_in[0];
    const float* w_off  = (const float*)d_in[1];
    const float* b_off  = (const float*)d_in[2];
    const float* weight = (const float*)d_in[3];
    const float* bias   = (const float*)d_in[4];
    float* out = (float*)d_out;

    if (ws_size >= WS_BYTES) {
        float* pwbuf = (float*)d_ws;
        int*   abuf  = (int*)((float*)d_ws + 36 * NPIX);
        float* wpk1  = (float*)d_ws + 45 * NPIX;
        float* wpk2  = wpk1 + WPK1_N;
        hipLaunchKernelGGL(dcn_wprep, dim3((WPK1_N + WPK2_N + 255) / 256), dim3(256),
                           0, stream, w_off, weight, wpk1, wpk2);
        hipLaunchKernelGGL(dcn_k1, dim3(PGRPS), dim3(256), 0, stream,
                           x, wpk1, b_off, pwbuf, abuf);
        hipLaunchKernelGGL(dcn_k2, dim3(PGRPS), dim3(512), 0, stream,
                           x, wpk2, bias, pwbuf, abuf, out);
    } else {
        hipLaunchKernelGGL(dcn_r1, dim3(NPIX / 64), dim3(64), 0, stream,
                           x, w_off, b_off, weight, bias, out);
    }
}